// Round 1
// baseline (1122.028 us; speedup 1.0000x reference)
//
#include <hip/hip_runtime.h>

#define THREADS 256

// ---------- degree / normalization ----------
__global__ void k_deg(const int* __restrict__ dst, int* __restrict__ deg, int E) {
    int e = blockIdx.x * blockDim.x + threadIdx.x;
    if (e < E) atomicAdd(&deg[dst[e]], 1);
}

__global__ void k_dinv(const int* __restrict__ deg, float* __restrict__ dinv, int n) {
    int i = blockIdx.x * blockDim.x + threadIdx.x;
    if (i < n) dinv[i] = rsqrtf((float)deg[i] + 1.0f);
}

// ---------- C[n,64] = X[n,fin] @ W[fin,64], W staged in LDS ----------
// block = 256 threads = 4 row-groups x 64 cols; each thread does 4 rows.
// 16 rows per block; N=100000 is divisible by 16.
__global__ void k_gemm64(const float* __restrict__ X, const float* __restrict__ W,
                         float* __restrict__ C, int n, int fin) {
    extern __shared__ float wlds[];           // fin * 64 floats
    int tid = threadIdx.x;
    for (int i = tid; i < fin * 64; i += THREADS) wlds[i] = W[i];
    __syncthreads();
    int col = tid & 63;
    int r0  = blockIdx.x * 16 + (tid >> 6) * 4;
    if (r0 >= n) return;
    const float* x0 = X + (size_t)r0 * fin;
    float a0 = 0.f, a1 = 0.f, a2 = 0.f, a3 = 0.f;
    for (int k = 0; k < fin; ++k) {
        float w = wlds[k * 64 + col];         // 2-way LDS alias: free
        a0 = fmaf(x0[k],            w, a0);
        a1 = fmaf(x0[fin + k],      w, a1);
        a2 = fmaf(x0[2 * fin + k],  w, a2);
        a3 = fmaf(x0[3 * fin + k],  w, a3);
    }
    C[(size_t)r0 * 64 + col]       = a0;
    if (r0 + 1 < n) C[(size_t)(r0 + 1) * 64 + col] = a1;
    if (r0 + 2 < n) C[(size_t)(r0 + 2) * 64 + col] = a2;
    if (r0 + 3 < n) C[(size_t)(r0 + 3) * 64 + col] = a3;
}

// ---------- edge-parallel scatter: agg[dst] += h[src] * dinv[src]*dinv[dst] ----------
// 64 consecutive threads (one row per wave-half... actually one row per 64 lanes)
__global__ void k_agg(const float* __restrict__ H, const int* __restrict__ src,
                      const int* __restrict__ dst, const float* __restrict__ dinv,
                      float* __restrict__ agg, int E) {
    int t = blockIdx.x * blockDim.x + threadIdx.x;   // E*64 = 102.4M < 2^31
    int e = t >> 6;
    if (e >= E) return;
    int c = t & 63;
    int s = src[e], d = dst[e];
    float nrm = dinv[s] * dinv[d];
    atomicAdd(&agg[(size_t)d * 64 + c], H[(size_t)s * 64 + c] * nrm);
}

// ---------- fused self-loop + bias + ReLU (in place on agg) ----------
__global__ void k_relu_self(float* __restrict__ agg, const float* __restrict__ Hlin,
                            const float* __restrict__ dinv, const float* __restrict__ b,
                            int n) {
    int t = blockIdx.x * blockDim.x + threadIdx.x;
    if (t >= n * 64) return;
    int i = t >> 6, c = t & 63;
    float di = dinv[i];
    float v = agg[t] + Hlin[t] * di * di + b[c];
    agg[t] = v > 0.f ? v : 0.f;
}

// ---------- mean-pool scatter ----------
__global__ void k_pool(const float* __restrict__ H, const int* __restrict__ dict,
                       float* __restrict__ pooled, int n) {
    int t = blockIdx.x * blockDim.x + threadIdx.x;
    if (t >= n * 64) return;
    int i = t >> 6, c = t & 63;
    atomicAdd(&pooled[(size_t)dict[i] * 64 + c], H[t]);
}

__global__ void k_cnt(const int* __restrict__ dict, float* __restrict__ cnt, int n) {
    int i = blockIdx.x * blockDim.x + threadIdx.x;
    if (i < n) atomicAdd(&cnt[dict[i]], 1.0f);
}

// ---------- mean + FC(64->16) + log_softmax ----------
// block = 256 = 16 nodes x 16 lanes
__global__ void k_final(const float* __restrict__ pooled, const float* __restrict__ cnt,
                        const float* __restrict__ Wfc, const float* __restrict__ bfc,
                        float* __restrict__ out, int n) {
    __shared__ float wf[64 * 16];
    __shared__ float prow[16][65];            // +1 pad: kill 4-way bank conflict
    int tid  = threadIdx.x;
    for (int i = tid; i < 64 * 16; i += THREADS) wf[i] = Wfc[i];
    int nl = tid >> 4, lane = tid & 15;
    int node = blockIdx.x * 16 + nl;
    if (node < n) {
        float inv = 1.0f / fmaxf(cnt[node], 1.0f);
        float4 v = ((const float4*)(pooled + (size_t)node * 64))[lane];
        prow[nl][lane * 4 + 0] = v.x * inv;
        prow[nl][lane * 4 + 1] = v.y * inv;
        prow[nl][lane * 4 + 2] = v.z * inv;
        prow[nl][lane * 4 + 3] = v.w * inv;
    }
    __syncthreads();
    if (node >= n) return;
    float acc = bfc[lane];
    #pragma unroll
    for (int k = 0; k < 64; ++k)
        acc = fmaf(prow[nl][k], wf[k * 16 + lane], acc);
    // log_softmax over the 16 lanes of this node
    float m = acc;
    for (int o = 8; o; o >>= 1) m = fmaxf(m, __shfl_xor(m, o, 16));
    float ex = __expf(acc - m);
    float s = ex;
    for (int o = 8; o; o >>= 1) s += __shfl_xor(s, o, 16);
    out[(size_t)node * 16 + lane] = acc - m - __logf(s);
}

extern "C" void kernel_launch(void* const* d_in, const int* in_sizes, int n_in,
                              void* d_out, int out_size, void* d_ws, size_t ws_size,
                              hipStream_t stream) {
    const float* x    = (const float*)d_in[0];
    const int*   ei   = (const int*)d_in[1];
    const int*   dict = (const int*)d_in[2];
    const float* W1   = (const float*)d_in[3];
    const float* b1   = (const float*)d_in[4];
    const float* W2   = (const float*)d_in[5];
    const float* b2   = (const float*)d_in[6];
    const float* Wfc  = (const float*)d_in[7];
    const float* bfc  = (const float*)d_in[8];

    const int N  = in_sizes[2];          // 100000
    const int E  = in_sizes[1] / 2;      // 1600000
    const int IN = in_sizes[0] / N;      // 128
    const int* src = ei;
    const int* dst = ei + E;

    float* bufA = (float*)d_ws;                    // N*64
    float* bufB = bufA + (size_t)N * 64;           // N*64
    float* bufC = bufB + (size_t)N * 64;           // N*64
    float* dinv = bufC + (size_t)N * 64;           // N
    int*   deg  = (int*)(dinv + N);                // N
    float* cnt  = (float*)(deg + N);               // N

    const int gN    = (N + THREADS - 1) / THREADS;
    const int gE    = (E + THREADS - 1) / THREADS;
    const int gNE   = (N * 64 + THREADS - 1) / THREADS;     // 25000
    const int gAgg  = (int)(((long long)E * 64 + THREADS - 1) / THREADS); // 400000
    const int gRows = (N + 15) / 16;                        // 6250

    // normalization
    hipMemsetAsync(deg, 0, (size_t)N * sizeof(int), stream);
    hipMemsetAsync(cnt, 0, (size_t)N * sizeof(float), stream);
    k_deg<<<gE, THREADS, 0, stream>>>(dst, deg, E);
    k_dinv<<<gN, THREADS, 0, stream>>>(deg, dinv, N);

    // layer 1: h1 = X@W1 -> bufA ; agg -> bufB ; h = relu(...) in bufB
    k_gemm64<<<gRows, THREADS, IN * 64 * sizeof(float), stream>>>(x, W1, bufA, N, IN);
    hipMemsetAsync(bufB, 0, (size_t)N * 64 * sizeof(float), stream);
    k_agg<<<gAgg, THREADS, 0, stream>>>(bufA, src, dst, dinv, bufB, E);
    k_relu_self<<<gNE, THREADS, 0, stream>>>(bufB, bufA, dinv, b1, N);

    // layer 2: h2 = h@W2 -> bufC ; agg -> bufA ; h_final = relu(...) in bufA
    k_gemm64<<<gRows, THREADS, 64 * 64 * sizeof(float), stream>>>(bufB, W2, bufC, N, 64);
    hipMemsetAsync(bufA, 0, (size_t)N * 64 * sizeof(float), stream);
    k_agg<<<gAgg, THREADS, 0, stream>>>(bufC, src, dst, dinv, bufA, E);
    k_relu_self<<<gNE, THREADS, 0, stream>>>(bufA, bufC, dinv, b2, N);

    // pool: sums -> bufB, counts -> cnt
    hipMemsetAsync(bufB, 0, (size_t)N * 64 * sizeof(float), stream);
    k_pool<<<gNE, THREADS, 0, stream>>>(bufA, dict, bufB, N);
    k_cnt<<<gN, THREADS, 0, stream>>>(dict, cnt, N);

    // mean + FC + log_softmax
    k_final<<<gRows, THREADS, 0, stream>>>(bufB, cnt, Wfc, bfc, (float*)d_out, N);
}

// Round 2
// 711.198 us; speedup vs baseline: 1.5777x; 1.5777x over previous
//
#include <hip/hip_runtime.h>

#define THREADS 256

// ---------- degree / normalization ----------
__global__ void k_deg(const int* __restrict__ dst, int* __restrict__ deg, int E) {
    int e = blockIdx.x * blockDim.x + threadIdx.x;
    if (e < E) atomicAdd(&deg[dst[e]], 1);
}

__global__ void k_dinv(const int* __restrict__ deg, float* __restrict__ dinv, int n) {
    int i = blockIdx.x * blockDim.x + threadIdx.x;
    if (i < n) dinv[i] = rsqrtf((float)deg[i] + 1.0f);
}

// ---------- CSR build: block sums -> scan block sums -> offsets/cursor -> bucket ----
__global__ void k_bsum(const int* __restrict__ deg, int* __restrict__ bsum, int n) {
    __shared__ int s[THREADS];
    int i = blockIdx.x * THREADS + threadIdx.x;
    s[threadIdx.x] = (i < n) ? deg[i] : 0;
    __syncthreads();
    for (int o = THREADS / 2; o; o >>= 1) {
        if (threadIdx.x < o) s[threadIdx.x] += s[threadIdx.x + o];
        __syncthreads();
    }
    if (threadIdx.x == 0) bsum[blockIdx.x] = s[0];
}

// single block of 512; requires nb <= 512 (nb = ceil(N/256) = 391 here)
__global__ void k_bscan(int* __restrict__ bsum, int nb) {
    __shared__ int s[512];
    int v = (threadIdx.x < nb) ? bsum[threadIdx.x] : 0;
    s[threadIdx.x] = v;
    __syncthreads();
    for (int o = 1; o < 512; o <<= 1) {
        int t = (threadIdx.x >= (unsigned)o) ? s[threadIdx.x - o] : 0;
        __syncthreads();
        s[threadIdx.x] += t;
        __syncthreads();
    }
    if (threadIdx.x < nb) bsum[threadIdx.x] = s[threadIdx.x] - v;  // exclusive
}

__global__ void k_offsets(const int* __restrict__ deg, const int* __restrict__ bsum,
                          int* __restrict__ off, int* __restrict__ cursor, int n, int E) {
    __shared__ int s[THREADS];
    int i = blockIdx.x * THREADS + threadIdx.x;
    int v = (i < n) ? deg[i] : 0;
    s[threadIdx.x] = v;
    __syncthreads();
    for (int o = 1; o < THREADS; o <<= 1) {
        int t = (threadIdx.x >= (unsigned)o) ? s[threadIdx.x - o] : 0;
        __syncthreads();
        s[threadIdx.x] += t;
        __syncthreads();
    }
    if (i < n) {
        int excl = bsum[blockIdx.x] + s[threadIdx.x] - v;
        off[i] = excl;
        cursor[i] = excl;
        if (i == n - 1) off[n] = E;
    }
}

__global__ void k_bucket(const int* __restrict__ src, const int* __restrict__ dst,
                         const float* __restrict__ dinv, int* __restrict__ cursor,
                         int* __restrict__ csr_src, float* __restrict__ csr_nrm, int E) {
    int e = blockIdx.x * blockDim.x + threadIdx.x;
    if (e >= E) return;
    int s = src[e], d = dst[e];
    int pos = atomicAdd(&cursor[d], 1);
    csr_src[pos] = s;
    csr_nrm[pos] = dinv[s] * dinv[d];
}

// ---------- C[n,64] = X[n,fin] @ W[fin,64], W staged in LDS ----------
__global__ void k_gemm64(const float* __restrict__ X, const float* __restrict__ W,
                         float* __restrict__ C, int n, int fin) {
    extern __shared__ float wlds[];           // fin * 64 floats
    int tid = threadIdx.x;
    for (int i = tid; i < fin * 64; i += THREADS) wlds[i] = W[i];
    __syncthreads();
    int col = tid & 63;
    int r0  = blockIdx.x * 16 + (tid >> 6) * 4;
    if (r0 >= n) return;
    const float* x0 = X + (size_t)r0 * fin;
    float a0 = 0.f, a1 = 0.f, a2 = 0.f, a3 = 0.f;
    for (int k = 0; k < fin; ++k) {
        float w = wlds[k * 64 + col];
        a0 = fmaf(x0[k],            w, a0);
        a1 = fmaf(x0[fin + k],      w, a1);
        a2 = fmaf(x0[2 * fin + k],  w, a2);
        a3 = fmaf(x0[3 * fin + k],  w, a3);
    }
    C[(size_t)r0 * 64 + col]       = a0;
    if (r0 + 1 < n) C[(size_t)(r0 + 1) * 64 + col] = a1;
    if (r0 + 2 < n) C[(size_t)(r0 + 2) * 64 + col] = a2;
    if (r0 + 3 < n) C[(size_t)(r0 + 3) * 64 + col] = a3;
}

// ---------- CSR gather + fused self-loop + bias + ReLU ----------
// 64 lanes per node (lane = feature col); register accumulation, single write.
__global__ void k_gcn_gather(const float* __restrict__ H, const int* __restrict__ csr_src,
                             const float* __restrict__ csr_nrm, const int* __restrict__ off,
                             const float* __restrict__ dinv, const float* __restrict__ b,
                             float* __restrict__ out, int n) {
    int t = blockIdx.x * blockDim.x + threadIdx.x;
    int node = t >> 6;
    if (node >= n) return;
    int c = t & 63;
    int j = off[node], end = off[node + 1];
    float acc = 0.f;
    for (; j + 1 < end; j += 2) {              // unroll 2: overlap the row loads
        int   s0 = csr_src[j],     s1 = csr_src[j + 1];
        float n0 = csr_nrm[j],     n1 = csr_nrm[j + 1];
        float h0 = H[(size_t)s0 * 64 + c];
        float h1 = H[(size_t)s1 * 64 + c];
        acc = fmaf(h0, n0, acc);
        acc = fmaf(h1, n1, acc);
    }
    if (j < end)
        acc = fmaf(H[(size_t)csr_src[j] * 64 + c], csr_nrm[j], acc);
    float di = dinv[node];
    float v = acc + H[(size_t)node * 64 + c] * di * di + b[c];
    out[(size_t)node * 64 + c] = v > 0.f ? v : 0.f;
}

// ---------- mean-pool scatter ----------
__global__ void k_pool(const float* __restrict__ H, const int* __restrict__ dict,
                       float* __restrict__ pooled, int n) {
    int t = blockIdx.x * blockDim.x + threadIdx.x;
    if (t >= n * 64) return;
    int i = t >> 6, c = t & 63;
    atomicAdd(&pooled[(size_t)dict[i] * 64 + c], H[t]);
}

__global__ void k_cnt(const int* __restrict__ dict, float* __restrict__ cnt, int n) {
    int i = blockIdx.x * blockDim.x + threadIdx.x;
    if (i < n) atomicAdd(&cnt[dict[i]], 1.0f);
}

// ---------- mean + FC(64->16) + log_softmax ----------
__global__ void k_final(const float* __restrict__ pooled, const float* __restrict__ cnt,
                        const float* __restrict__ Wfc, const float* __restrict__ bfc,
                        float* __restrict__ out, int n) {
    __shared__ float wf[64 * 16];
    __shared__ float prow[16][65];            // +1 pad: kill bank conflicts
    int tid  = threadIdx.x;
    for (int i = tid; i < 64 * 16; i += THREADS) wf[i] = Wfc[i];
    int nl = tid >> 4, lane = tid & 15;
    int node = blockIdx.x * 16 + nl;
    if (node < n) {
        float inv = 1.0f / fmaxf(cnt[node], 1.0f);
        float4 v = ((const float4*)(pooled + (size_t)node * 64))[lane];
        prow[nl][lane * 4 + 0] = v.x * inv;
        prow[nl][lane * 4 + 1] = v.y * inv;
        prow[nl][lane * 4 + 2] = v.z * inv;
        prow[nl][lane * 4 + 3] = v.w * inv;
    }
    __syncthreads();
    if (node >= n) return;
    float acc = bfc[lane];
    #pragma unroll
    for (int k = 0; k < 64; ++k)
        acc = fmaf(prow[nl][k], wf[k * 16 + lane], acc);
    float m = acc;
    for (int o = 8; o; o >>= 1) m = fmaxf(m, __shfl_xor(m, o, 16));
    float ex = __expf(acc - m);
    float s = ex;
    for (int o = 8; o; o >>= 1) s += __shfl_xor(s, o, 16);
    out[(size_t)node * 16 + lane] = acc - m - __logf(s);
}

extern "C" void kernel_launch(void* const* d_in, const int* in_sizes, int n_in,
                              void* d_out, int out_size, void* d_ws, size_t ws_size,
                              hipStream_t stream) {
    const float* x    = (const float*)d_in[0];
    const int*   ei   = (const int*)d_in[1];
    const int*   dict = (const int*)d_in[2];
    const float* W1   = (const float*)d_in[3];
    const float* b1   = (const float*)d_in[4];
    const float* W2   = (const float*)d_in[5];
    const float* b2   = (const float*)d_in[6];
    const float* Wfc  = (const float*)d_in[7];
    const float* bfc  = (const float*)d_in[8];

    const int N  = in_sizes[2];          // 100000
    const int E  = in_sizes[1] / 2;      // 1600000
    const int IN = in_sizes[0] / N;      // 128
    const int* src = ei;
    const int* dst = ei + E;

    // workspace layout (all 4-byte types): ~66 MB total
    float* bufA    = (float*)d_ws;                 // N*64
    float* bufB    = bufA + (size_t)N * 64;        // N*64
    float* dinv    = bufB + (size_t)N * 64;        // N
    int*   deg     = (int*)(dinv + N);             // N
    float* cnt     = (float*)(deg + N);            // N
    int*   off     = (int*)(cnt + N);              // N+1
    int*   cursor  = off + (N + 1);                // N
    int*   bsum    = cursor + N;                   // 512
    int*   csr_src = bsum + 512;                   // E
    float* csr_nrm = (float*)(csr_src + E);        // E

    const int gN    = (N + THREADS - 1) / THREADS;          // 391
    const int gE    = (E + THREADS - 1) / THREADS;          // 6250
    const int gNE   = (N * 64 + THREADS - 1) / THREADS;     // 25000
    const int gRows = (N + 15) / 16;                        // 6250

    // normalization + CSR build (once; reused by both layers)
    hipMemsetAsync(deg, 0, (size_t)N * sizeof(int), stream);
    hipMemsetAsync(cnt, 0, (size_t)N * sizeof(float), stream);
    k_deg<<<gE, THREADS, 0, stream>>>(dst, deg, E);
    k_dinv<<<gN, THREADS, 0, stream>>>(deg, dinv, N);
    k_bsum<<<gN, THREADS, 0, stream>>>(deg, bsum, N);
    k_bscan<<<1, 512, 0, stream>>>(bsum, gN);
    k_offsets<<<gN, THREADS, 0, stream>>>(deg, bsum, off, cursor, N, E);
    k_bucket<<<gE, THREADS, 0, stream>>>(src, dst, dinv, cursor, csr_src, csr_nrm, E);

    // layer 1: h1_lin = X@W1 -> A ; h1 = relu(gather(A)+self+b1) -> B
    k_gemm64<<<gRows, THREADS, IN * 64 * sizeof(float), stream>>>(x, W1, bufA, N, IN);
    k_gcn_gather<<<gNE, THREADS, 0, stream>>>(bufA, csr_src, csr_nrm, off, dinv, b1, bufB, N);

    // layer 2: h2_lin = h1@W2 -> A ; h2 = relu(gather(A)+self+b2) -> B
    k_gemm64<<<gRows, THREADS, 64 * 64 * sizeof(float), stream>>>(bufB, W2, bufA, N, 64);
    k_gcn_gather<<<gNE, THREADS, 0, stream>>>(bufA, csr_src, csr_nrm, off, dinv, b2, bufB, N);

    // pool: sums -> A (zeroed), counts -> cnt
    hipMemsetAsync(bufA, 0, (size_t)N * 64 * sizeof(float), stream);
    k_pool<<<gNE, THREADS, 0, stream>>>(bufB, dict, bufA, N);
    k_cnt<<<gN, THREADS, 0, stream>>>(dict, cnt, N);

    // mean + FC + log_softmax
    k_final<<<gRows, THREADS, 0, stream>>>(bufA, cnt, Wfc, bfc, (float*)d_out, N);
}

// Round 3
// 650.205 us; speedup vs baseline: 1.7257x; 1.0938x over previous
//
#include <hip/hip_runtime.h>

#define THREADS 256

// ---------- degree / normalization ----------
__global__ void k_deg(const int* __restrict__ dst, int* __restrict__ deg, int E) {
    int e = blockIdx.x * blockDim.x + threadIdx.x;
    if (e < E) atomicAdd(&deg[dst[e]], 1);
}

__global__ void k_dinv(const int* __restrict__ deg, float* __restrict__ dinv, int n) {
    int i = blockIdx.x * blockDim.x + threadIdx.x;
    if (i < n) dinv[i] = rsqrtf((float)deg[i] + 1.0f);
}

// ---------- CSR build: block sums -> scan block sums -> offsets/cursor -> bucket ----
__global__ void k_bsum(const int* __restrict__ deg, int* __restrict__ bsum, int n) {
    __shared__ int s[THREADS];
    int i = blockIdx.x * THREADS + threadIdx.x;
    s[threadIdx.x] = (i < n) ? deg[i] : 0;
    __syncthreads();
    for (int o = THREADS / 2; o; o >>= 1) {
        if (threadIdx.x < o) s[threadIdx.x] += s[threadIdx.x + o];
        __syncthreads();
    }
    if (threadIdx.x == 0) bsum[blockIdx.x] = s[0];
}

// single block of 512; requires nb <= 512 (nb = ceil(N/256) = 391 here)
__global__ void k_bscan(int* __restrict__ bsum, int nb) {
    __shared__ int s[512];
    int v = (threadIdx.x < nb) ? bsum[threadIdx.x] : 0;
    s[threadIdx.x] = v;
    __syncthreads();
    for (int o = 1; o < 512; o <<= 1) {
        int t = (threadIdx.x >= (unsigned)o) ? s[threadIdx.x - o] : 0;
        __syncthreads();
        s[threadIdx.x] += t;
        __syncthreads();
    }
    if (threadIdx.x < nb) bsum[threadIdx.x] = s[threadIdx.x] - v;  // exclusive
}

__global__ void k_offsets(const int* __restrict__ deg, const int* __restrict__ bsum,
                          int* __restrict__ off, int* __restrict__ cursor, int n, int E) {
    __shared__ int s[THREADS];
    int i = blockIdx.x * THREADS + threadIdx.x;
    int v = (i < n) ? deg[i] : 0;
    s[threadIdx.x] = v;
    __syncthreads();
    for (int o = 1; o < THREADS; o <<= 1) {
        int t = (threadIdx.x >= (unsigned)o) ? s[threadIdx.x - o] : 0;
        __syncthreads();
        s[threadIdx.x] += t;
        __syncthreads();
    }
    if (i < n) {
        int excl = bsum[blockIdx.x] + s[threadIdx.x] - v;
        off[i] = excl;
        cursor[i] = excl;
        if (i == n - 1) off[n] = E;
    }
}

// single scattered 4B store per edge (norm is reconstructed from dinv at gather time)
__global__ void k_bucket(const int* __restrict__ src, const int* __restrict__ dst,
                         int* __restrict__ cursor, int* __restrict__ csr_src, int E) {
    int e = blockIdx.x * blockDim.x + threadIdx.x;
    if (e >= E) return;
    int pos = atomicAdd(&cursor[dst[e]], 1);
    csr_src[pos] = src[e];
}

// ---------- C[n,64] = X[n,fin] @ W[fin,64], W staged in LDS ----------
__global__ void k_gemm64(const float* __restrict__ X, const float* __restrict__ W,
                         float* __restrict__ C, int n, int fin) {
    extern __shared__ float wlds[];           // fin * 64 floats
    int tid = threadIdx.x;
    for (int i = tid; i < fin * 64; i += THREADS) wlds[i] = W[i];
    __syncthreads();
    int col = tid & 63;
    int r0  = blockIdx.x * 16 + (tid >> 6) * 4;
    if (r0 >= n) return;
    const float* x0 = X + (size_t)r0 * fin;
    float a0 = 0.f, a1 = 0.f, a2 = 0.f, a3 = 0.f;
    for (int k = 0; k < fin; ++k) {
        float w = wlds[k * 64 + col];
        a0 = fmaf(x0[k],            w, a0);
        a1 = fmaf(x0[fin + k],      w, a1);
        a2 = fmaf(x0[2 * fin + k],  w, a2);
        a3 = fmaf(x0[3 * fin + k],  w, a3);
    }
    C[(size_t)r0 * 64 + col]       = a0;
    if (r0 + 1 < n) C[(size_t)(r0 + 1) * 64 + col] = a1;
    if (r0 + 2 < n) C[(size_t)(r0 + 2) * 64 + col] = a2;
    if (r0 + 3 < n) C[(size_t)(r0 + 3) * 64 + col] = a3;
}

// ---------- layer-1: CSR gather + self-loop + bias + ReLU -> out ----------
// 64 lanes per node; unroll-4 with independent accumulators to keep 4+ row
// loads in flight (row hits are L2/L3, ~200-600 cyc).
__global__ void k_gcn_gather(const float* __restrict__ H, const int* __restrict__ csr_src,
                             const int* __restrict__ off, const float* __restrict__ dinv,
                             const float* __restrict__ b, float* __restrict__ out, int n) {
    int t = blockIdx.x * blockDim.x + threadIdx.x;
    int node = t >> 6;
    if (node >= n) return;
    int c = t & 63;
    int j = off[node], end = off[node + 1];
    float dn = dinv[node];
    float a0 = 0.f, a1 = 0.f, a2 = 0.f, a3 = 0.f;
    for (; j + 3 < end; j += 4) {
        int s0 = csr_src[j], s1 = csr_src[j + 1], s2 = csr_src[j + 2], s3 = csr_src[j + 3];
        float w0 = dinv[s0], w1 = dinv[s1], w2 = dinv[s2], w3 = dinv[s3];
        float h0 = H[(size_t)s0 * 64 + c];
        float h1 = H[(size_t)s1 * 64 + c];
        float h2 = H[(size_t)s2 * 64 + c];
        float h3 = H[(size_t)s3 * 64 + c];
        a0 = fmaf(h0, w0, a0); a1 = fmaf(h1, w1, a1);
        a2 = fmaf(h2, w2, a2); a3 = fmaf(h3, w3, a3);
    }
    for (; j < end; ++j) {
        int s = csr_src[j];
        a0 = fmaf(H[(size_t)s * 64 + c], dinv[s], a0);
    }
    float acc = ((a0 + a1) + (a2 + a3)) * dn;       // dinv[node] factored out
    float v = acc + H[(size_t)node * 64 + c] * dn * dn + b[c];
    out[(size_t)node * 64 + c] = v > 0.f ? v : 0.f;
}

// ---------- layer-2: gather + ReLU + fused FC(64->16) + 16-dim pool scatter ----
// h2 is never written to global; q = relu(h2) @ Wfc (16 floats/node) is
// atomically added into pool16[dict[node]] — one 64B line per node.
__global__ void k_gcn_gather_fc(const float* __restrict__ H, const int* __restrict__ csr_src,
                                const int* __restrict__ off, const float* __restrict__ dinv,
                                const float* __restrict__ b, const float* __restrict__ Wfc,
                                const int* __restrict__ dict, float* __restrict__ pool16,
                                int n) {
    __shared__ float wt[16 * 65];     // Wfc transposed [r][c], pad 65: <=2-way banks
    __shared__ float hrow[4][64];
    int tid = threadIdx.x;
    for (int i = tid; i < 64 * 16; i += THREADS) {
        int cc = i >> 4, r = i & 15;
        wt[r * 65 + cc] = Wfc[i];     // Wfc[cc*16 + r]
    }
    int t = blockIdx.x * blockDim.x + tid;
    int node = t >> 6;
    int c = t & 63;
    int nl = tid >> 6;
    float v = 0.f;
    if (node < n) {
        int j = off[node], end = off[node + 1];
        float dn = dinv[node];
        float a0 = 0.f, a1 = 0.f, a2 = 0.f, a3 = 0.f;
        for (; j + 3 < end; j += 4) {
            int s0 = csr_src[j], s1 = csr_src[j + 1], s2 = csr_src[j + 2], s3 = csr_src[j + 3];
            float w0 = dinv[s0], w1 = dinv[s1], w2 = dinv[s2], w3 = dinv[s3];
            float h0 = H[(size_t)s0 * 64 + c];
            float h1 = H[(size_t)s1 * 64 + c];
            float h2 = H[(size_t)s2 * 64 + c];
            float h3 = H[(size_t)s3 * 64 + c];
            a0 = fmaf(h0, w0, a0); a1 = fmaf(h1, w1, a1);
            a2 = fmaf(h2, w2, a2); a3 = fmaf(h3, w3, a3);
        }
        for (; j < end; ++j) {
            int s = csr_src[j];
            a0 = fmaf(H[(size_t)s * 64 + c], dinv[s], a0);
        }
        float acc = ((a0 + a1) + (a2 + a3)) * dn;
        float hv = acc + H[(size_t)node * 64 + c] * dn * dn + b[c];
        v = hv > 0.f ? hv : 0.f;
    }
    hrow[nl][c] = v;
    __syncthreads();
    // FC partials: lane = (g, r), g = c>>4 covers c-range [g*16, g*16+16)
    int g = c >> 4, r = c & 15;
    float p = 0.f;
    #pragma unroll
    for (int i = 0; i < 16; ++i) {
        int cc = g * 16 + i;
        p = fmaf(hrow[nl][cc], wt[r * 65 + cc], p);
    }
    p += __shfl_xor(p, 16);   // + partial of g^1
    p += __shfl_xor(p, 32);   // + partial of g^2
    if (node < n && g == 0)
        atomicAdd(&pool16[(size_t)dict[node] * 16 + r], p);
}

__global__ void k_cnt(const int* __restrict__ dict, float* __restrict__ cnt, int n) {
    int i = blockIdx.x * blockDim.x + threadIdx.x;
    if (i < n) atomicAdd(&cnt[dict[i]], 1.0f);
}

// ---------- mean + bias + log_softmax over 16 classes ----------
// block = 256 = 16 nodes x 16 lanes
__global__ void k_final16(const float* __restrict__ pool16, const float* __restrict__ cnt,
                          const float* __restrict__ bfc, float* __restrict__ out, int n) {
    int tid = threadIdx.x;
    int nl = tid >> 4, lane = tid & 15;
    int node = blockIdx.x * 16 + nl;
    if (node >= n) return;
    float inv = 1.0f / fmaxf(cnt[node], 1.0f);
    float acc = pool16[(size_t)node * 16 + lane] * inv + bfc[lane];
    float m = acc;
    for (int o = 8; o; o >>= 1) m = fmaxf(m, __shfl_xor(m, o, 16));
    float ex = __expf(acc - m);
    float s = ex;
    for (int o = 8; o; o >>= 1) s += __shfl_xor(s, o, 16);
    out[(size_t)node * 16 + lane] = acc - m - __logf(s);
}

extern "C" void kernel_launch(void* const* d_in, const int* in_sizes, int n_in,
                              void* d_out, int out_size, void* d_ws, size_t ws_size,
                              hipStream_t stream) {
    const float* x    = (const float*)d_in[0];
    const int*   ei   = (const int*)d_in[1];
    const int*   dict = (const int*)d_in[2];
    const float* W1   = (const float*)d_in[3];
    const float* b1   = (const float*)d_in[4];
    const float* W2   = (const float*)d_in[5];
    const float* b2   = (const float*)d_in[6];
    const float* Wfc  = (const float*)d_in[7];
    const float* bfc  = (const float*)d_in[8];

    const int N  = in_sizes[2];          // 100000
    const int E  = in_sizes[1] / 2;      // 1600000
    const int IN = in_sizes[0] / N;      // 128
    const int* src = ei;
    const int* dst = ei + E;

    // workspace layout (all 4-byte types): ~66 MB total
    float* bufA    = (float*)d_ws;                 // N*64
    float* bufB    = bufA + (size_t)N * 64;        // N*64
    float* dinv    = bufB + (size_t)N * 64;        // N
    int*   deg     = (int*)(dinv + N);             // N
    float* cnt     = (float*)(deg + N);            // N
    int*   off     = (int*)(cnt + N);              // N+1
    int*   cursor  = off + (N + 1);                // N
    int*   bsum    = cursor + N;                   // 512
    int*   csr_src = bsum + 512;                   // E
    float* pool16  = (float*)(csr_src + E);        // N*16

    const int gN    = (N + THREADS - 1) / THREADS;          // 391
    const int gE    = (E + THREADS - 1) / THREADS;          // 6250
    const int gNE   = (N * 64 + THREADS - 1) / THREADS;     // 25000
    const int gRows = (N + 15) / 16;                        // 6250

    // normalization + CSR build (once; reused by both layers)
    hipMemsetAsync(deg, 0, (size_t)N * sizeof(int), stream);
    hipMemsetAsync(cnt, 0, (size_t)N * sizeof(float), stream);
    hipMemsetAsync(pool16, 0, (size_t)N * 16 * sizeof(float), stream);
    k_deg<<<gE, THREADS, 0, stream>>>(dst, deg, E);
    k_dinv<<<gN, THREADS, 0, stream>>>(deg, dinv, N);
    k_bsum<<<gN, THREADS, 0, stream>>>(deg, bsum, N);
    k_bscan<<<1, 512, 0, stream>>>(bsum, gN);
    k_offsets<<<gN, THREADS, 0, stream>>>(deg, bsum, off, cursor, N, E);
    k_bucket<<<gE, THREADS, 0, stream>>>(src, dst, cursor, csr_src, E);

    // layer 1: h1_lin = X@W1 -> A ; h1 = relu(gather(A)+self+b1) -> B
    k_gemm64<<<gRows, THREADS, IN * 64 * sizeof(float), stream>>>(x, W1, bufA, N, IN);
    k_gcn_gather<<<gNE, THREADS, 0, stream>>>(bufA, csr_src, off, dinv, b1, bufB, N);

    // layer 2: h2_lin = h1@W2 -> A ; fused gather+ReLU+FC+pool-scatter
    k_gemm64<<<gRows, THREADS, 64 * 64 * sizeof(float), stream>>>(bufB, W2, bufA, N, 64);
    k_gcn_gather_fc<<<gNE, THREADS, 0, stream>>>(bufA, csr_src, off, dinv, b2, Wfc,
                                                 dict, pool16, N);
    k_cnt<<<gN, THREADS, 0, stream>>>(dict, cnt, N);

    // mean + bias + log_softmax
    k_final16<<<gRows, THREADS, 0, stream>>>(pool16, cnt, bfc, (float*)d_out, N);
}

// Round 4
// 549.672 us; speedup vs baseline: 2.0413x; 1.1829x over previous
//
#include <hip/hip_runtime.h>

#define THREADS 256

// ---------- degree + per-edge rank ----------
// rank[e] = position of edge e among edges sharing its dst (order arbitrary).
__global__ void k_deg(const int* __restrict__ dst, int* __restrict__ deg,
                      int* __restrict__ rank, int E) {
    int e = blockIdx.x * blockDim.x + threadIdx.x;
    if (e < E) rank[e] = atomicAdd(&deg[dst[e]], 1);
}

__global__ void k_dinv(const int* __restrict__ deg, float* __restrict__ dinv, int n) {
    int i = blockIdx.x * blockDim.x + threadIdx.x;
    if (i < n) dinv[i] = rsqrtf((float)deg[i] + 1.0f);
}

// ---------- CSR build: block sums -> scan block sums -> offsets -> bucket ----
__global__ void k_bsum(const int* __restrict__ deg, int* __restrict__ bsum, int n) {
    __shared__ int s[THREADS];
    int i = blockIdx.x * THREADS + threadIdx.x;
    s[threadIdx.x] = (i < n) ? deg[i] : 0;
    __syncthreads();
    for (int o = THREADS / 2; o; o >>= 1) {
        if (threadIdx.x < o) s[threadIdx.x] += s[threadIdx.x + o];
        __syncthreads();
    }
    if (threadIdx.x == 0) bsum[blockIdx.x] = s[0];
}

// single block of 512; requires nb <= 512 (nb = ceil(N/256) = 391 here)
__global__ void k_bscan(int* __restrict__ bsum, int nb) {
    __shared__ int s[512];
    int v = (threadIdx.x < nb) ? bsum[threadIdx.x] : 0;
    s[threadIdx.x] = v;
    __syncthreads();
    for (int o = 1; o < 512; o <<= 1) {
        int t = (threadIdx.x >= (unsigned)o) ? s[threadIdx.x - o] : 0;
        __syncthreads();
        s[threadIdx.x] += t;
        __syncthreads();
    }
    if (threadIdx.x < nb) bsum[threadIdx.x] = s[threadIdx.x] - v;  // exclusive
}

__global__ void k_offsets(const int* __restrict__ deg, const int* __restrict__ bsum,
                          int* __restrict__ off, int n, int E) {
    __shared__ int s[THREADS];
    int i = blockIdx.x * THREADS + threadIdx.x;
    int v = (i < n) ? deg[i] : 0;
    s[threadIdx.x] = v;
    __syncthreads();
    for (int o = 1; o < THREADS; o <<= 1) {
        int t = (threadIdx.x >= (unsigned)o) ? s[threadIdx.x - o] : 0;
        __syncthreads();
        s[threadIdx.x] += t;
        __syncthreads();
    }
    if (i < n) {
        off[i] = bsum[blockIdx.x] + s[threadIdx.x] - v;
        if (i == n - 1) off[n] = E;
    }
}

// one fire-and-forget scattered 4B store per edge; no atomics
__global__ void k_bucket(const int* __restrict__ src, const int* __restrict__ dst,
                         const int* __restrict__ rank, const int* __restrict__ off,
                         int* __restrict__ csr_src, int E) {
    int e = blockIdx.x * blockDim.x + threadIdx.x;
    if (e >= E) return;
    csr_src[off[dst[e]] + rank[e]] = src[e];
}

// ---------- C[n,64] = X[n,fin] @ W[fin,64], W staged in LDS, float4 X loads ----
__global__ void k_gemm64(const float* __restrict__ X, const float* __restrict__ W,
                         float* __restrict__ C, int n, int fin) {
    extern __shared__ float wlds[];           // fin * 64 floats
    int tid = threadIdx.x;
    for (int i = tid; i < fin * 64; i += THREADS) wlds[i] = W[i];
    __syncthreads();
    int col = tid & 63;
    int r0  = blockIdx.x * 16 + (tid >> 6) * 4;
    if (r0 >= n) return;
    const float* x0 = X + (size_t)r0 * fin;
    float a0 = 0.f, a1 = 0.f, a2 = 0.f, a3 = 0.f;
    for (int k = 0; k < fin; k += 4) {
        float4 xv0 = *(const float4*)(x0 + k);
        float4 xv1 = *(const float4*)(x0 + fin + k);
        float4 xv2 = *(const float4*)(x0 + 2 * fin + k);
        float4 xv3 = *(const float4*)(x0 + 3 * fin + k);
        float w0 = wlds[(k + 0) * 64 + col];
        float w1 = wlds[(k + 1) * 64 + col];
        float w2 = wlds[(k + 2) * 64 + col];
        float w3 = wlds[(k + 3) * 64 + col];
        a0 = fmaf(xv0.x, w0, a0); a0 = fmaf(xv0.y, w1, a0);
        a0 = fmaf(xv0.z, w2, a0); a0 = fmaf(xv0.w, w3, a0);
        a1 = fmaf(xv1.x, w0, a1); a1 = fmaf(xv1.y, w1, a1);
        a1 = fmaf(xv1.z, w2, a1); a1 = fmaf(xv1.w, w3, a1);
        a2 = fmaf(xv2.x, w0, a2); a2 = fmaf(xv2.y, w1, a2);
        a2 = fmaf(xv2.z, w2, a2); a2 = fmaf(xv2.w, w3, a2);
        a3 = fmaf(xv3.x, w0, a3); a3 = fmaf(xv3.y, w1, a3);
        a3 = fmaf(xv3.z, w2, a3); a3 = fmaf(xv3.w, w3, a3);
    }
    C[(size_t)r0 * 64 + col]       = a0;
    if (r0 + 1 < n) C[(size_t)(r0 + 1) * 64 + col] = a1;
    if (r0 + 2 < n) C[(size_t)(r0 + 2) * 64 + col] = a2;
    if (r0 + 3 < n) C[(size_t)(r0 + 3) * 64 + col] = a3;
}

// ---------- layer-1: CSR gather + self-loop + bias + ReLU -> out ----------
__global__ void k_gcn_gather(const float* __restrict__ H, const int* __restrict__ csr_src,
                             const int* __restrict__ off, const float* __restrict__ dinv,
                             const float* __restrict__ b, float* __restrict__ out, int n) {
    int t = blockIdx.x * blockDim.x + threadIdx.x;
    int node = t >> 6;
    if (node >= n) return;
    int c = t & 63;
    int j = off[node], end = off[node + 1];
    float dn = dinv[node];
    float a0 = 0.f, a1 = 0.f, a2 = 0.f, a3 = 0.f;
    for (; j + 3 < end; j += 4) {
        int s0 = csr_src[j], s1 = csr_src[j + 1], s2 = csr_src[j + 2], s3 = csr_src[j + 3];
        float w0 = dinv[s0], w1 = dinv[s1], w2 = dinv[s2], w3 = dinv[s3];
        float h0 = H[(size_t)s0 * 64 + c];
        float h1 = H[(size_t)s1 * 64 + c];
        float h2 = H[(size_t)s2 * 64 + c];
        float h3 = H[(size_t)s3 * 64 + c];
        a0 = fmaf(h0, w0, a0); a1 = fmaf(h1, w1, a1);
        a2 = fmaf(h2, w2, a2); a3 = fmaf(h3, w3, a3);
    }
    for (; j < end; ++j) {
        int s = csr_src[j];
        a0 = fmaf(H[(size_t)s * 64 + c], dinv[s], a0);
    }
    float acc = ((a0 + a1) + (a2 + a3)) * dn;
    float v = acc + H[(size_t)node * 64 + c] * dn * dn + b[c];
    out[(size_t)node * 64 + c] = v > 0.f ? v : 0.f;
}

// ---------- layer-2: gather + ReLU + fused FC(64->16) + 16-dim pool scatter ----
__global__ void k_gcn_gather_fc(const float* __restrict__ H, const int* __restrict__ csr_src,
                                const int* __restrict__ off, const float* __restrict__ dinv,
                                const float* __restrict__ b, const float* __restrict__ Wfc,
                                const int* __restrict__ dict, float* __restrict__ pool16,
                                int n) {
    __shared__ float wt[16 * 65];     // Wfc transposed [r][c], pad 65
    __shared__ float hrow[4][64];
    int tid = threadIdx.x;
    for (int i = tid; i < 64 * 16; i += THREADS) {
        int cc = i >> 4, r = i & 15;
        wt[r * 65 + cc] = Wfc[i];     // Wfc[cc*16 + r]
    }
    int t = blockIdx.x * blockDim.x + tid;
    int node = t >> 6;
    int c = t & 63;
    int nl = tid >> 6;
    float v = 0.f;
    if (node < n) {
        int j = off[node], end = off[node + 1];
        float dn = dinv[node];
        float a0 = 0.f, a1 = 0.f, a2 = 0.f, a3 = 0.f;
        for (; j + 3 < end; j += 4) {
            int s0 = csr_src[j], s1 = csr_src[j + 1], s2 = csr_src[j + 2], s3 = csr_src[j + 3];
            float w0 = dinv[s0], w1 = dinv[s1], w2 = dinv[s2], w3 = dinv[s3];
            float h0 = H[(size_t)s0 * 64 + c];
            float h1 = H[(size_t)s1 * 64 + c];
            float h2 = H[(size_t)s2 * 64 + c];
            float h3 = H[(size_t)s3 * 64 + c];
            a0 = fmaf(h0, w0, a0); a1 = fmaf(h1, w1, a1);
            a2 = fmaf(h2, w2, a2); a3 = fmaf(h3, w3, a3);
        }
        for (; j < end; ++j) {
            int s = csr_src[j];
            a0 = fmaf(H[(size_t)s * 64 + c], dinv[s], a0);
        }
        float acc = ((a0 + a1) + (a2 + a3)) * dn;
        float hv = acc + H[(size_t)node * 64 + c] * dn * dn + b[c];
        v = hv > 0.f ? hv : 0.f;
    }
    hrow[nl][c] = v;
    __syncthreads();
    int g = c >> 4, r = c & 15;
    float p = 0.f;
    #pragma unroll
    for (int i = 0; i < 16; ++i) {
        int cc = g * 16 + i;
        p = fmaf(hrow[nl][cc], wt[r * 65 + cc], p);
    }
    p += __shfl_xor(p, 16);
    p += __shfl_xor(p, 32);
    if (node < n && g == 0)
        atomicAdd(&pool16[(size_t)dict[node] * 16 + r], p);
}

__global__ void k_cnt(const int* __restrict__ dict, float* __restrict__ cnt, int n) {
    int i = blockIdx.x * blockDim.x + threadIdx.x;
    if (i < n) atomicAdd(&cnt[dict[i]], 1.0f);
}

// ---------- mean + bias + log_softmax over 16 classes ----------
__global__ void k_final16(const float* __restrict__ pool16, const float* __restrict__ cnt,
                          const float* __restrict__ bfc, float* __restrict__ out, int n) {
    int tid = threadIdx.x;
    int nl = tid >> 4, lane = tid & 15;
    int node = blockIdx.x * 16 + nl;
    if (node >= n) return;
    float inv = 1.0f / fmaxf(cnt[node], 1.0f);
    float acc = pool16[(size_t)node * 16 + lane] * inv + bfc[lane];
    float m = acc;
    for (int o = 8; o; o >>= 1) m = fmaxf(m, __shfl_xor(m, o, 16));
    float ex = __expf(acc - m);
    float s = ex;
    for (int o = 8; o; o >>= 1) s += __shfl_xor(s, o, 16);
    out[(size_t)node * 16 + lane] = acc - m - __logf(s);
}

extern "C" void kernel_launch(void* const* d_in, const int* in_sizes, int n_in,
                              void* d_out, int out_size, void* d_ws, size_t ws_size,
                              hipStream_t stream) {
    const float* x    = (const float*)d_in[0];
    const int*   ei   = (const int*)d_in[1];
    const int*   dict = (const int*)d_in[2];
    const float* W1   = (const float*)d_in[3];
    const float* b1   = (const float*)d_in[4];
    const float* W2   = (const float*)d_in[5];
    const float* b2   = (const float*)d_in[6];
    const float* Wfc  = (const float*)d_in[7];
    const float* bfc  = (const float*)d_in[8];

    const int N  = in_sizes[2];          // 100000
    const int E  = in_sizes[1] / 2;      // 1600000
    const int IN = in_sizes[0] / N;      // 128
    const int* src = ei;
    const int* dst = ei + E;

    // workspace layout (all 4-byte types): ~72 MB total
    float* bufA    = (float*)d_ws;                 // N*64
    float* bufB    = bufA + (size_t)N * 64;        // N*64
    float* dinv    = bufB + (size_t)N * 64;        // N
    int*   deg     = (int*)(dinv + N);             // N
    float* cnt     = (float*)(deg + N);            // N
    int*   off     = (int*)(cnt + N);              // N+1
    int*   bsum    = off + (N + 1);                // 512
    int*   rank    = bsum + 512;                   // E
    int*   csr_src = rank + E;                     // E
    float* pool16  = (float*)(csr_src + E);        // N*16

    const int gN    = (N + THREADS - 1) / THREADS;          // 391
    const int gE    = (E + THREADS - 1) / THREADS;          // 6250
    const int gNE   = (N * 64 + THREADS - 1) / THREADS;     // 25000
    const int gRows = (N + 15) / 16;                        // 6250

    // normalization + CSR build (once; reused by both layers)
    hipMemsetAsync(deg, 0, (size_t)N * sizeof(int), stream);
    hipMemsetAsync(cnt, 0, (size_t)N * sizeof(float), stream);
    hipMemsetAsync(pool16, 0, (size_t)N * 16 * sizeof(float), stream);
    k_deg<<<gE, THREADS, 0, stream>>>(dst, deg, rank, E);
    k_dinv<<<gN, THREADS, 0, stream>>>(deg, dinv, N);
    k_bsum<<<gN, THREADS, 0, stream>>>(deg, bsum, N);
    k_bscan<<<1, 512, 0, stream>>>(bsum, gN);
    k_offsets<<<gN, THREADS, 0, stream>>>(deg, bsum, off, N, E);
    k_bucket<<<gE, THREADS, 0, stream>>>(src, dst, rank, off, csr_src, E);

    // layer 1: h1_lin = X@W1 -> A ; h1 = relu(gather(A)+self+b1) -> B
    k_gemm64<<<gRows, THREADS, IN * 64 * sizeof(float), stream>>>(x, W1, bufA, N, IN);
    k_gcn_gather<<<gNE, THREADS, 0, stream>>>(bufA, csr_src, off, dinv, b1, bufB, N);

    // layer 2: h2_lin = h1@W2 -> A ; fused gather+ReLU+FC+pool-scatter
    k_gemm64<<<gRows, THREADS, 64 * 64 * sizeof(float), stream>>>(bufB, W2, bufA, N, 64);
    k_gcn_gather_fc<<<gNE, THREADS, 0, stream>>>(bufA, csr_src, off, dinv, b2, Wfc,
                                                 dict, pool16, N);
    k_cnt<<<gN, THREADS, 0, stream>>>(dict, cnt, N);

    // mean + bias + log_softmax
    k_final16<<<gRows, THREADS, 0, stream>>>(pool16, cnt, bfc, (float*)d_out, N);
}

// Round 5
// 430.268 us; speedup vs baseline: 2.6077x; 1.2775x over previous
//
#include <hip/hip_runtime.h>

#define THREADS 256
#define KC 32

// ---------- degree + per-edge rank ----------
__global__ void k_deg(const int* __restrict__ dst, int* __restrict__ deg,
                      int* __restrict__ rank, int E) {
    int e = blockIdx.x * blockDim.x + threadIdx.x;
    if (e < E) rank[e] = atomicAdd(&deg[dst[e]], 1);
}

__global__ void k_dinv(const int* __restrict__ deg, float* __restrict__ dinv, int n) {
    int i = blockIdx.x * blockDim.x + threadIdx.x;
    if (i < n) dinv[i] = rsqrtf((float)deg[i] + 1.0f);
}

// ---------- CSR build: block sums -> scan block sums -> offsets -> bucket ----
__global__ void k_bsum(const int* __restrict__ deg, int* __restrict__ bsum, int n) {
    __shared__ int s[THREADS];
    int i = blockIdx.x * THREADS + threadIdx.x;
    s[threadIdx.x] = (i < n) ? deg[i] : 0;
    __syncthreads();
    for (int o = THREADS / 2; o; o >>= 1) {
        if (threadIdx.x < o) s[threadIdx.x] += s[threadIdx.x + o];
        __syncthreads();
    }
    if (threadIdx.x == 0) bsum[blockIdx.x] = s[0];
}

// single block of 512; requires nb <= 512 (nb = ceil(N/256) = 391 here)
__global__ void k_bscan(int* __restrict__ bsum, int nb) {
    __shared__ int s[512];
    int v = (threadIdx.x < nb) ? bsum[threadIdx.x] : 0;
    s[threadIdx.x] = v;
    __syncthreads();
    for (int o = 1; o < 512; o <<= 1) {
        int t = (threadIdx.x >= (unsigned)o) ? s[threadIdx.x - o] : 0;
        __syncthreads();
        s[threadIdx.x] += t;
        __syncthreads();
    }
    if (threadIdx.x < nb) bsum[threadIdx.x] = s[threadIdx.x] - v;  // exclusive
}

__global__ void k_offsets(const int* __restrict__ deg, const int* __restrict__ bsum,
                          int* __restrict__ off, int n, int E) {
    __shared__ int s[THREADS];
    int i = blockIdx.x * THREADS + threadIdx.x;
    int v = (i < n) ? deg[i] : 0;
    s[threadIdx.x] = v;
    __syncthreads();
    for (int o = 1; o < THREADS; o <<= 1) {
        int t = (threadIdx.x >= (unsigned)o) ? s[threadIdx.x - o] : 0;
        __syncthreads();
        s[threadIdx.x] += t;
        __syncthreads();
    }
    if (i < n) {
        off[i] = bsum[blockIdx.x] + s[threadIdx.x] - v;
        if (i == n - 1) off[n] = E;
    }
}

// one fire-and-forget scattered 4B store per edge; no atomics
__global__ void k_bucket(const int* __restrict__ src, const int* __restrict__ dst,
                         const int* __restrict__ rank, const int* __restrict__ off,
                         int* __restrict__ csr_src, int E) {
    int e = blockIdx.x * blockDim.x + threadIdx.x;
    if (e >= E) return;
    csr_src[off[dst[e]] + rank[e]] = src[e];
}

// ---------- tiled GEMM: C[n,64] = X[n,fin] @ W[fin,64] ----------
// 64x64 tile, K-chunks of 32, X staged TRANSPOSED in LDS (pad 68 => aligned
// b128, 2-way banks = free). Each thread owns a 4x4 register tile: per k,
// 2x ds_read_b128 + 16 FMA (16 independent chains) => VALU-bound.
__global__ __launch_bounds__(THREADS) void
k_gemm_tile(const float* __restrict__ X, const float* __restrict__ W,
            float* __restrict__ C, int n, int fin) {
    __shared__ float Xs[KC][68];
    __shared__ float Ws[KC][64];
    int tid = threadIdx.x;
    int r0  = blockIdx.x * 64;

    int tx4 = (tid & 15) * 4;          // col quad
    int ty4 = (tid >> 4) * 4;          // row quad

    // staging maps
    int sxr = tid >> 2;                // X: row 0..63
    int sxk = (tid & 3) * 4;           // X: k quad within half-chunk
    int swk = tid >> 4;                // W: k 0..15
    int swc = (tid & 15) * 4;          // W: col quad

    int xrow = r0 + sxr; if (xrow >= n) xrow = n - 1;   // clamp (results discarded)
    const float* xptr = X + (size_t)xrow * fin;

    float4 acc0 = {0,0,0,0}, acc1 = {0,0,0,0}, acc2 = {0,0,0,0}, acc3 = {0,0,0,0};

    for (int kc = 0; kc < fin; kc += KC) {
        float4 xa = *(const float4*)(xptr + kc + sxk);
        float4 xb = *(const float4*)(xptr + kc + 16 + sxk);
        float4 wa = *(const float4*)(W + (size_t)(kc + swk) * 64 + swc);
        float4 wb = *(const float4*)(W + (size_t)(kc + swk + 16) * 64 + swc);
        __syncthreads();
        Xs[sxk + 0][sxr] = xa.x; Xs[sxk + 1][sxr] = xa.y;
        Xs[sxk + 2][sxr] = xa.z; Xs[sxk + 3][sxr] = xa.w;
        Xs[16 + sxk + 0][sxr] = xb.x; Xs[16 + sxk + 1][sxr] = xb.y;
        Xs[16 + sxk + 2][sxr] = xb.z; Xs[16 + sxk + 3][sxr] = xb.w;
        *(float4*)&Ws[swk][swc]      = wa;
        *(float4*)&Ws[swk + 16][swc] = wb;
        __syncthreads();
        #pragma unroll 8
        for (int k = 0; k < KC; ++k) {
            float4 a = *(const float4*)&Xs[k][ty4];
            float4 b = *(const float4*)&Ws[k][tx4];
            acc0.x = fmaf(a.x, b.x, acc0.x); acc0.y = fmaf(a.x, b.y, acc0.y);
            acc0.z = fmaf(a.x, b.z, acc0.z); acc0.w = fmaf(a.x, b.w, acc0.w);
            acc1.x = fmaf(a.y, b.x, acc1.x); acc1.y = fmaf(a.y, b.y, acc1.y);
            acc1.z = fmaf(a.y, b.z, acc1.z); acc1.w = fmaf(a.y, b.w, acc1.w);
            acc2.x = fmaf(a.z, b.x, acc2.x); acc2.y = fmaf(a.z, b.y, acc2.y);
            acc2.z = fmaf(a.z, b.z, acc2.z); acc2.w = fmaf(a.z, b.w, acc2.w);
            acc3.x = fmaf(a.w, b.x, acc3.x); acc3.y = fmaf(a.w, b.y, acc3.y);
            acc3.z = fmaf(a.w, b.z, acc3.z); acc3.w = fmaf(a.w, b.w, acc3.w);
        }
    }
    int row = r0 + ty4;
    if (row < n)     *(float4*)(C + (size_t)row * 64 + tx4)       = acc0;
    if (row + 1 < n) *(float4*)(C + (size_t)(row + 1) * 64 + tx4) = acc1;
    if (row + 2 < n) *(float4*)(C + (size_t)(row + 2) * 64 + tx4) = acc2;
    if (row + 3 < n) *(float4*)(C + (size_t)(row + 3) * 64 + tx4) = acc3;
}

// ---------- layer-1: CSR gather + self-loop + bias + ReLU -> out ----------
__global__ void k_gcn_gather(const float* __restrict__ H, const int* __restrict__ csr_src,
                             const int* __restrict__ off, const float* __restrict__ dinv,
                             const float* __restrict__ b, float* __restrict__ out, int n) {
    int t = blockIdx.x * blockDim.x + threadIdx.x;
    int node = t >> 6;
    if (node >= n) return;
    int c = t & 63;
    int j = off[node], end = off[node + 1];
    float dn = dinv[node];
    float a0 = 0.f, a1 = 0.f, a2 = 0.f, a3 = 0.f;
    for (; j + 3 < end; j += 4) {
        int s0 = csr_src[j], s1 = csr_src[j + 1], s2 = csr_src[j + 2], s3 = csr_src[j + 3];
        float w0 = dinv[s0], w1 = dinv[s1], w2 = dinv[s2], w3 = dinv[s3];
        float h0 = H[(size_t)s0 * 64 + c];
        float h1 = H[(size_t)s1 * 64 + c];
        float h2 = H[(size_t)s2 * 64 + c];
        float h3 = H[(size_t)s3 * 64 + c];
        a0 = fmaf(h0, w0, a0); a1 = fmaf(h1, w1, a1);
        a2 = fmaf(h2, w2, a2); a3 = fmaf(h3, w3, a3);
    }
    for (; j < end; ++j) {
        int s = csr_src[j];
        a0 = fmaf(H[(size_t)s * 64 + c], dinv[s], a0);
    }
    float acc = ((a0 + a1) + (a2 + a3)) * dn;
    float v = acc + H[(size_t)node * 64 + c] * dn * dn + b[c];
    out[(size_t)node * 64 + c] = v > 0.f ? v : 0.f;
}

// ---------- layer-2: gather + ReLU + fused FC(64->16) + 16-dim pool scatter ----
__global__ void k_gcn_gather_fc(const float* __restrict__ H, const int* __restrict__ csr_src,
                                const int* __restrict__ off, const float* __restrict__ dinv,
                                const float* __restrict__ b, const float* __restrict__ Wfc,
                                const int* __restrict__ dict, float* __restrict__ pool16,
                                int n) {
    __shared__ float wt[16 * 65];     // Wfc transposed [r][c], pad 65
    __shared__ float hrow[4][64];
    int tid = threadIdx.x;
    for (int i = tid; i < 64 * 16; i += THREADS) {
        int cc = i >> 4, r = i & 15;
        wt[r * 65 + cc] = Wfc[i];     // Wfc[cc*16 + r]
    }
    int t = blockIdx.x * blockDim.x + tid;
    int node = t >> 6;
    int c = t & 63;
    int nl = tid >> 6;
    float v = 0.f;
    if (node < n) {
        int j = off[node], end = off[node + 1];
        float dn = dinv[node];
        float a0 = 0.f, a1 = 0.f, a2 = 0.f, a3 = 0.f;
        for (; j + 3 < end; j += 4) {
            int s0 = csr_src[j], s1 = csr_src[j + 1], s2 = csr_src[j + 2], s3 = csr_src[j + 3];
            float w0 = dinv[s0], w1 = dinv[s1], w2 = dinv[s2], w3 = dinv[s3];
            float h0 = H[(size_t)s0 * 64 + c];
            float h1 = H[(size_t)s1 * 64 + c];
            float h2 = H[(size_t)s2 * 64 + c];
            float h3 = H[(size_t)s3 * 64 + c];
            a0 = fmaf(h0, w0, a0); a1 = fmaf(h1, w1, a1);
            a2 = fmaf(h2, w2, a2); a3 = fmaf(h3, w3, a3);
        }
        for (; j < end; ++j) {
            int s = csr_src[j];
            a0 = fmaf(H[(size_t)s * 64 + c], dinv[s], a0);
        }
        float acc = ((a0 + a1) + (a2 + a3)) * dn;
        float hv = acc + H[(size_t)node * 64 + c] * dn * dn + b[c];
        v = hv > 0.f ? hv : 0.f;
    }
    hrow[nl][c] = v;
    __syncthreads();
    int g = c >> 4, r = c & 15;
    float p = 0.f;
    #pragma unroll
    for (int i = 0; i < 16; ++i) {
        int cc = g * 16 + i;
        p = fmaf(hrow[nl][cc], wt[r * 65 + cc], p);
    }
    p += __shfl_xor(p, 16);
    p += __shfl_xor(p, 32);
    if (node < n && g == 0)
        atomicAdd(&pool16[(size_t)dict[node] * 16 + r], p);
}

__global__ void k_cnt(const int* __restrict__ dict, float* __restrict__ cnt, int n) {
    int i = blockIdx.x * blockDim.x + threadIdx.x;
    if (i < n) atomicAdd(&cnt[dict[i]], 1.0f);
}

// ---------- mean + bias + log_softmax over 16 classes ----------
__global__ void k_final16(const float* __restrict__ pool16, const float* __restrict__ cnt,
                          const float* __restrict__ bfc, float* __restrict__ out, int n) {
    int tid = threadIdx.x;
    int nl = tid >> 4, lane = tid & 15;
    int node = blockIdx.x * 16 + nl;
    if (node >= n) return;
    float inv = 1.0f / fmaxf(cnt[node], 1.0f);
    float acc = pool16[(size_t)node * 16 + lane] * inv + bfc[lane];
    float m = acc;
    for (int o = 8; o; o >>= 1) m = fmaxf(m, __shfl_xor(m, o, 16));
    float ex = __expf(acc - m);
    float s = ex;
    for (int o = 8; o; o >>= 1) s += __shfl_xor(s, o, 16);
    out[(size_t)node * 16 + lane] = acc - m - __logf(s);
}

extern "C" void kernel_launch(void* const* d_in, const int* in_sizes, int n_in,
                              void* d_out, int out_size, void* d_ws, size_t ws_size,
                              hipStream_t stream) {
    const float* x    = (const float*)d_in[0];
    const int*   ei   = (const int*)d_in[1];
    const int*   dict = (const int*)d_in[2];
    const float* W1   = (const float*)d_in[3];
    const float* b1   = (const float*)d_in[4];
    const float* W2   = (const float*)d_in[5];
    const float* b2   = (const float*)d_in[6];
    const float* Wfc  = (const float*)d_in[7];
    const float* bfc  = (const float*)d_in[8];

    const int N  = in_sizes[2];          // 100000
    const int E  = in_sizes[1] / 2;      // 1600000
    const int IN = in_sizes[0] / N;      // 128
    const int* src = ei;
    const int* dst = ei + E;

    // workspace layout (all 4-byte types): ~72 MB total
    float* bufA    = (float*)d_ws;                 // N*64
    float* bufB    = bufA + (size_t)N * 64;        // N*64
    float* dinv    = bufB + (size_t)N * 64;        // N
    int*   deg     = (int*)(dinv + N);             // N
    float* cnt     = (float*)(deg + N);            // N
    int*   off     = (int*)(cnt + N);              // N+1
    int*   bsum    = off + (N + 1);                // 512
    int*   rank    = bsum + 512;                   // E
    int*   csr_src = rank + E;                     // E
    float* pool16  = (float*)(csr_src + E);        // N*16

    const int gN    = (N + THREADS - 1) / THREADS;          // 391
    const int gE    = (E + THREADS - 1) / THREADS;          // 6250
    const int gNE   = (N * 64 + THREADS - 1) / THREADS;     // 25000
    const int gTile = (N + 63) / 64;                        // 1563
    const int gRows = (N + 15) / 16;                        // 6250

    // normalization + CSR build (once; reused by both layers)
    hipMemsetAsync(deg, 0, (size_t)N * sizeof(int), stream);
    hipMemsetAsync(cnt, 0, (size_t)N * sizeof(float), stream);
    hipMemsetAsync(pool16, 0, (size_t)N * 16 * sizeof(float), stream);
    k_deg<<<gE, THREADS, 0, stream>>>(dst, deg, rank, E);
    k_dinv<<<gN, THREADS, 0, stream>>>(deg, dinv, N);
    k_bsum<<<gN, THREADS, 0, stream>>>(deg, bsum, N);
    k_bscan<<<1, 512, 0, stream>>>(bsum, gN);
    k_offsets<<<gN, THREADS, 0, stream>>>(deg, bsum, off, N, E);
    k_bucket<<<gE, THREADS, 0, stream>>>(src, dst, rank, off, csr_src, E);

    // layer 1: h1_lin = X@W1 -> A ; h1 = relu(gather(A)+self+b1) -> B
    k_gemm_tile<<<gTile, THREADS, 0, stream>>>(x, W1, bufA, N, IN);
    k_gcn_gather<<<gNE, THREADS, 0, stream>>>(bufA, csr_src, off, dinv, b1, bufB, N);

    // layer 2: h2_lin = h1@W2 -> A ; fused gather+ReLU+FC+pool-scatter
    k_gemm_tile<<<gTile, THREADS, 0, stream>>>(bufB, W2, bufA, N, 64);
    k_gcn_gather_fc<<<gNE, THREADS, 0, stream>>>(bufA, csr_src, off, dinv, b2, Wfc,
                                                 dict, pool16, N);
    k_cnt<<<gN, THREADS, 0, stream>>>(dict, cnt, N);

    // mean + bias + log_softmax
    k_final16<<<gRows, THREADS, 0, stream>>>(pool16, cnt, bfc, (float*)d_out, N);
}

// Round 6
// 418.872 us; speedup vs baseline: 2.6787x; 1.0272x over previous
//
#include <hip/hip_runtime.h>

#define THREADS 256
#define KC 32

// ---- bf16 helpers (RNE pack, cheap unpack) ----
__device__ inline ushort f2bf(float v) {
    union { float f; unsigned u; } a; a.f = v;
    unsigned r = a.u + 0x7fff + ((a.u >> 16) & 1);
    return (ushort)(r >> 16);
}
__device__ inline float bf2f(ushort u) {
    union { unsigned u; float f; } a; a.u = (unsigned)u << 16; return a.f;
}
__device__ inline float bflo(unsigned v) {
    union { unsigned u; float f; } a; a.u = v << 16; return a.f;
}
__device__ inline float bfhi(unsigned v) {
    union { unsigned u; float f; } a; a.u = v & 0xffff0000u; return a.f;
}

// ---------- degree + per-edge rank ----------
__global__ void k_deg(const int* __restrict__ dst, int* __restrict__ deg,
                      int* __restrict__ rank, int E) {
    int e = blockIdx.x * blockDim.x + threadIdx.x;
    if (e < E) rank[e] = atomicAdd(&deg[dst[e]], 1);
}

// ---------- CSR build: block sums -> scan -> offsets(+dinv) -> bucket ----------
__global__ void k_bsum(const int* __restrict__ deg, int* __restrict__ bsum, int n) {
    __shared__ int s[THREADS];
    int i = blockIdx.x * THREADS + threadIdx.x;
    s[threadIdx.x] = (i < n) ? deg[i] : 0;
    __syncthreads();
    for (int o = THREADS / 2; o; o >>= 1) {
        if (threadIdx.x < o) s[threadIdx.x] += s[threadIdx.x + o];
        __syncthreads();
    }
    if (threadIdx.x == 0) bsum[blockIdx.x] = s[0];
}

// single block of 512; requires nb <= 512 (nb = ceil(N/256) = 391 here)
__global__ void k_bscan(int* __restrict__ bsum, int nb) {
    __shared__ int s[512];
    int v = (threadIdx.x < nb) ? bsum[threadIdx.x] : 0;
    s[threadIdx.x] = v;
    __syncthreads();
    for (int o = 1; o < 512; o <<= 1) {
        int t = (threadIdx.x >= (unsigned)o) ? s[threadIdx.x - o] : 0;
        __syncthreads();
        s[threadIdx.x] += t;
        __syncthreads();
    }
    if (threadIdx.x < nb) bsum[threadIdx.x] = s[threadIdx.x] - v;  // exclusive
}

__global__ void k_offsets(const int* __restrict__ deg, const int* __restrict__ bsum,
                          int* __restrict__ off, float* __restrict__ dinv, int n, int E) {
    __shared__ int s[THREADS];
    int i = blockIdx.x * THREADS + threadIdx.x;
    int v = (i < n) ? deg[i] : 0;
    s[threadIdx.x] = v;
    __syncthreads();
    for (int o = 1; o < THREADS; o <<= 1) {
        int t = (threadIdx.x >= (unsigned)o) ? s[threadIdx.x - o] : 0;
        __syncthreads();
        s[threadIdx.x] += t;
        __syncthreads();
    }
    if (i < n) {
        off[i] = bsum[blockIdx.x] + s[threadIdx.x] - v;
        dinv[i] = rsqrtf((float)v + 1.0f);
        if (i == n - 1) off[n] = E;
    }
}

// one fire-and-forget scattered 4B store per edge; no atomics
__global__ void k_bucket(const int* __restrict__ src, const int* __restrict__ dst,
                         const int* __restrict__ rank, const int* __restrict__ off,
                         int* __restrict__ csr_src, int E) {
    int e = blockIdx.x * blockDim.x + threadIdx.x;
    if (e >= E) return;
    csr_src[off[dst[e]] + rank[e]] = src[e];
}

// ---------- tiled GEMM (fp32 X): C'[r,c] = (X@W)[r,c] * dinv[r] -> bf16 ----------
__global__ __launch_bounds__(THREADS) void
k_gemm_f32(const float* __restrict__ X, const float* __restrict__ W,
           const float* __restrict__ dinv, ushort* __restrict__ C, int n, int fin) {
    __shared__ float Xs[KC][68];
    __shared__ float Ws[KC][64];
    int tid = threadIdx.x;
    int r0  = blockIdx.x * 64;
    int tx4 = (tid & 15) * 4;
    int ty4 = (tid >> 4) * 4;
    int sxr = tid >> 2, sxk = (tid & 3) * 4;
    int swk = tid >> 4, swc = (tid & 15) * 4;
    int xrow = r0 + sxr; if (xrow >= n) xrow = n - 1;
    const float* xptr = X + (size_t)xrow * fin;
    float4 acc0 = {0,0,0,0}, acc1 = {0,0,0,0}, acc2 = {0,0,0,0}, acc3 = {0,0,0,0};
    for (int kc = 0; kc < fin; kc += KC) {
        float4 xa = *(const float4*)(xptr + kc + sxk);
        float4 xb = *(const float4*)(xptr + kc + 16 + sxk);
        float4 wa = *(const float4*)(W + (size_t)(kc + swk) * 64 + swc);
        float4 wb = *(const float4*)(W + (size_t)(kc + swk + 16) * 64 + swc);
        __syncthreads();
        Xs[sxk + 0][sxr] = xa.x; Xs[sxk + 1][sxr] = xa.y;
        Xs[sxk + 2][sxr] = xa.z; Xs[sxk + 3][sxr] = xa.w;
        Xs[16 + sxk + 0][sxr] = xb.x; Xs[16 + sxk + 1][sxr] = xb.y;
        Xs[16 + sxk + 2][sxr] = xb.z; Xs[16 + sxk + 3][sxr] = xb.w;
        *(float4*)&Ws[swk][swc]      = wa;
        *(float4*)&Ws[swk + 16][swc] = wb;
        __syncthreads();
        #pragma unroll 8
        for (int k = 0; k < KC; ++k) {
            float4 a = *(const float4*)&Xs[k][ty4];
            float4 b = *(const float4*)&Ws[k][tx4];
            acc0.x = fmaf(a.x, b.x, acc0.x); acc0.y = fmaf(a.x, b.y, acc0.y);
            acc0.z = fmaf(a.x, b.z, acc0.z); acc0.w = fmaf(a.x, b.w, acc0.w);
            acc1.x = fmaf(a.y, b.x, acc1.x); acc1.y = fmaf(a.y, b.y, acc1.y);
            acc1.z = fmaf(a.y, b.z, acc1.z); acc1.w = fmaf(a.y, b.w, acc1.w);
            acc2.x = fmaf(a.z, b.x, acc2.x); acc2.y = fmaf(a.z, b.y, acc2.y);
            acc2.z = fmaf(a.z, b.z, acc2.z); acc2.w = fmaf(a.z, b.w, acc2.w);
            acc3.x = fmaf(a.w, b.x, acc3.x); acc3.y = fmaf(a.w, b.y, acc3.y);
            acc3.z = fmaf(a.w, b.z, acc3.z); acc3.w = fmaf(a.w, b.w, acc3.w);
        }
    }
    int row = r0 + ty4;
    #pragma unroll
    for (int r = 0; r < 4; ++r) {
        if (row + r >= n) break;
        float dn = dinv[row + r];
        float4 a = r == 0 ? acc0 : r == 1 ? acc1 : r == 2 ? acc2 : acc3;
        ushort4 o;
        o.x = f2bf(a.x * dn); o.y = f2bf(a.y * dn);
        o.z = f2bf(a.z * dn); o.w = f2bf(a.w * dn);
        *(ushort4*)(C + (size_t)(row + r) * 64 + tx4) = o;
    }
}

// ---------- tiled GEMM (bf16 X, fin==64): C' = (X@W)*dinv -> bf16 ----------
__global__ __launch_bounds__(THREADS) void
k_gemm_bf16(const ushort* __restrict__ X, const float* __restrict__ W,
            const float* __restrict__ dinv, ushort* __restrict__ C, int n, int fin) {
    __shared__ float Xs[KC][68];
    __shared__ float Ws[KC][64];
    int tid = threadIdx.x;
    int r0  = blockIdx.x * 64;
    int tx4 = (tid & 15) * 4;
    int ty4 = (tid >> 4) * 4;
    int sxr = tid >> 2, sk8 = (tid & 3) * 8;
    int swk = tid >> 4, swc = (tid & 15) * 4;
    int xrow = r0 + sxr; if (xrow >= n) xrow = n - 1;
    const ushort* xptr = X + (size_t)xrow * fin;
    float4 acc0 = {0,0,0,0}, acc1 = {0,0,0,0}, acc2 = {0,0,0,0}, acc3 = {0,0,0,0};
    for (int kc = 0; kc < fin; kc += KC) {
        uint4 xv = *(const uint4*)(xptr + kc + sk8);        // 8 bf16
        float4 wa = *(const float4*)(W + (size_t)(kc + swk) * 64 + swc);
        float4 wb = *(const float4*)(W + (size_t)(kc + swk + 16) * 64 + swc);
        __syncthreads();
        Xs[sk8 + 0][sxr] = bflo(xv.x); Xs[sk8 + 1][sxr] = bfhi(xv.x);
        Xs[sk8 + 2][sxr] = bflo(xv.y); Xs[sk8 + 3][sxr] = bfhi(xv.y);
        Xs[sk8 + 4][sxr] = bflo(xv.z); Xs[sk8 + 5][sxr] = bfhi(xv.z);
        Xs[sk8 + 6][sxr] = bflo(xv.w); Xs[sk8 + 7][sxr] = bfhi(xv.w);
        *(float4*)&Ws[swk][swc]      = wa;
        *(float4*)&Ws[swk + 16][swc] = wb;
        __syncthreads();
        #pragma unroll 8
        for (int k = 0; k < KC; ++k) {
            float4 a = *(const float4*)&Xs[k][ty4];
            float4 b = *(const float4*)&Ws[k][tx4];
            acc0.x = fmaf(a.x, b.x, acc0.x); acc0.y = fmaf(a.x, b.y, acc0.y);
            acc0.z = fmaf(a.x, b.z, acc0.z); acc0.w = fmaf(a.x, b.w, acc0.w);
            acc1.x = fmaf(a.y, b.x, acc1.x); acc1.y = fmaf(a.y, b.y, acc1.y);
            acc1.z = fmaf(a.y, b.z, acc1.z); acc1.w = fmaf(a.y, b.w, acc1.w);
            acc2.x = fmaf(a.z, b.x, acc2.x); acc2.y = fmaf(a.z, b.y, acc2.y);
            acc2.z = fmaf(a.z, b.z, acc2.z); acc2.w = fmaf(a.z, b.w, acc2.w);
            acc3.x = fmaf(a.w, b.x, acc3.x); acc3.y = fmaf(a.w, b.y, acc3.y);
            acc3.z = fmaf(a.w, b.z, acc3.z); acc3.w = fmaf(a.w, b.w, acc3.w);
        }
    }
    int row = r0 + ty4;
    #pragma unroll
    for (int r = 0; r < 4; ++r) {
        if (row + r >= n) break;
        float dn = dinv[row + r];
        float4 a = r == 0 ? acc0 : r == 1 ? acc1 : r == 2 ? acc2 : acc3;
        ushort4 o;
        o.x = f2bf(a.x * dn); o.y = f2bf(a.y * dn);
        o.z = f2bf(a.z * dn); o.w = f2bf(a.w * dn);
        *(ushort4*)(C + (size_t)(row + r) * 64 + tx4) = o;
    }
}

// ---------- layer-1 gather: h1 = relu(dn*(sum rows + self) + b) -> bf16 ----------
// Rows are pre-scaled by dinv[src]; no per-edge weight loads.
__global__ void k_gcn_gather(const ushort* __restrict__ H, const int* __restrict__ csr_src,
                             const int* __restrict__ off, const float* __restrict__ dinv,
                             const float* __restrict__ b, ushort* __restrict__ out, int n) {
    int t = blockIdx.x * blockDim.x + threadIdx.x;
    int node = t >> 6;
    if (node >= n) return;
    int c = t & 63;
    int j = off[node], end = off[node + 1];
    float a0 = bf2f(H[(size_t)node * 64 + c]);   // self-loop joins the sum
    float a1 = 0.f, a2 = 0.f, a3 = 0.f;
    for (; j + 3 < end; j += 4) {
        int s0 = csr_src[j], s1 = csr_src[j + 1], s2 = csr_src[j + 2], s3 = csr_src[j + 3];
        float h0 = bf2f(H[(size_t)s0 * 64 + c]);
        float h1 = bf2f(H[(size_t)s1 * 64 + c]);
        float h2 = bf2f(H[(size_t)s2 * 64 + c]);
        float h3 = bf2f(H[(size_t)s3 * 64 + c]);
        a0 += h0; a1 += h1; a2 += h2; a3 += h3;
    }
    for (; j < end; ++j)
        a0 += bf2f(H[(size_t)csr_src[j] * 64 + c]);
    float v = ((a0 + a1) + (a2 + a3)) * dinv[node] + b[c];
    out[(size_t)node * 64 + c] = f2bf(v > 0.f ? v : 0.f);
}

// ---------- layer-2: gather + ReLU + fused FC(64->16) + 16-dim pool scatter ----
__global__ void k_gcn_gather_fc(const ushort* __restrict__ H, const int* __restrict__ csr_src,
                                const int* __restrict__ off, const float* __restrict__ dinv,
                                const float* __restrict__ b, const float* __restrict__ Wfc,
                                const int* __restrict__ dict, float* __restrict__ pool16,
                                int n) {
    __shared__ float wt[16 * 65];     // Wfc transposed [r][c], pad 65
    __shared__ float hrow[4][64];
    int tid = threadIdx.x;
    for (int i = tid; i < 64 * 16; i += THREADS) {
        int cc = i >> 4, r = i & 15;
        wt[r * 65 + cc] = Wfc[i];     // Wfc[cc*16 + r]
    }
    int t = blockIdx.x * blockDim.x + tid;
    int node = t >> 6;
    int c = t & 63;
    int nl = tid >> 6;
    float v = 0.f;
    if (node < n) {
        int j = off[node], end = off[node + 1];
        float a0 = bf2f(H[(size_t)node * 64 + c]);
        float a1 = 0.f, a2 = 0.f, a3 = 0.f;
        for (; j + 3 < end; j += 4) {
            int s0 = csr_src[j], s1 = csr_src[j + 1], s2 = csr_src[j + 2], s3 = csr_src[j + 3];
            float h0 = bf2f(H[(size_t)s0 * 64 + c]);
            float h1 = bf2f(H[(size_t)s1 * 64 + c]);
            float h2 = bf2f(H[(size_t)s2 * 64 + c]);
            float h3 = bf2f(H[(size_t)s3 * 64 + c]);
            a0 += h0; a1 += h1; a2 += h2; a3 += h3;
        }
        for (; j < end; ++j)
            a0 += bf2f(H[(size_t)csr_src[j] * 64 + c]);
        float hv = ((a0 + a1) + (a2 + a3)) * dinv[node] + b[c];
        v = hv > 0.f ? hv : 0.f;
    }
    hrow[nl][c] = v;
    __syncthreads();
    int g = c >> 4, r = c & 15;
    float p = 0.f;
    #pragma unroll
    for (int i = 0; i < 16; ++i) {
        int cc = g * 16 + i;
        p = fmaf(hrow[nl][cc], wt[r * 65 + cc], p);
    }
    p += __shfl_xor(p, 16);
    p += __shfl_xor(p, 32);
    if (node < n && g == 0)
        atomicAdd(&pool16[(size_t)dict[node] * 16 + r], p);
}

__global__ void k_cnt(const int* __restrict__ dict, float* __restrict__ cnt, int n) {
    int i = blockIdx.x * blockDim.x + threadIdx.x;
    if (i < n) atomicAdd(&cnt[dict[i]], 1.0f);
}

// ---------- mean + bias + log_softmax over 16 classes ----------
__global__ void k_final16(const float* __restrict__ pool16, const float* __restrict__ cnt,
                          const float* __restrict__ bfc, float* __restrict__ out, int n) {
    int tid = threadIdx.x;
    int nl = tid >> 4, lane = tid & 15;
    int node = blockIdx.x * 16 + nl;
    if (node >= n) return;
    float inv = 1.0f / fmaxf(cnt[node], 1.0f);
    float acc = pool16[(size_t)node * 16 + lane] * inv + bfc[lane];
    float m = acc;
    for (int o = 8; o; o >>= 1) m = fmaxf(m, __shfl_xor(m, o, 16));
    float ex = __expf(acc - m);
    float s = ex;
    for (int o = 8; o; o >>= 1) s += __shfl_xor(s, o, 16);
    out[(size_t)node * 16 + lane] = acc - m - __logf(s);
}

extern "C" void kernel_launch(void* const* d_in, const int* in_sizes, int n_in,
                              void* d_out, int out_size, void* d_ws, size_t ws_size,
                              hipStream_t stream) {
    const float* x    = (const float*)d_in[0];
    const int*   ei   = (const int*)d_in[1];
    const int*   dict = (const int*)d_in[2];
    const float* W1   = (const float*)d_in[3];
    const float* b1   = (const float*)d_in[4];
    const float* W2   = (const float*)d_in[5];
    const float* b2   = (const float*)d_in[6];
    const float* Wfc  = (const float*)d_in[7];
    const float* bfc  = (const float*)d_in[8];

    const int N  = in_sizes[2];          // 100000
    const int E  = in_sizes[1] / 2;      // 1600000
    const int IN = in_sizes[0] / N;      // 128
    const int* src = ei;
    const int* dst = ei + E;

    // workspace layout: bf16 H buffers + CSR + small arrays (~46 MB)
    ushort* bufA   = (ushort*)d_ws;                // N*64 bf16
    ushort* bufB   = bufA + (size_t)N * 64;        // N*64 bf16
    float* dinv    = (float*)(bufB + (size_t)N * 64);  // N
    int*   deg     = (int*)(dinv + N);             // N
    float* cnt     = (float*)(deg + N);            // N
    int*   off     = (int*)(cnt + N);              // N+1
    int*   bsum    = off + (N + 1);                // 512
    int*   rank    = bsum + 512;                   // E
    int*   csr_src = rank + E;                     // E
    float* pool16  = (float*)(csr_src + E);        // N*16

    const int gN    = (N + THREADS - 1) / THREADS;          // 391
    const int gE    = (E + THREADS - 1) / THREADS;          // 6250
    const int gNE   = (N * 64 + THREADS - 1) / THREADS;     // 25000
    const int gTile = (N + 63) / 64;                        // 1563
    const int gRows = (N + 15) / 16;                        // 6250

    // normalization + CSR build (once; reused by both layers)
    hipMemsetAsync(deg, 0, (size_t)N * sizeof(int), stream);
    hipMemsetAsync(cnt, 0, (size_t)N * sizeof(float), stream);
    hipMemsetAsync(pool16, 0, (size_t)N * 16 * sizeof(float), stream);
    k_deg<<<gE, THREADS, 0, stream>>>(dst, deg, rank, E);
    k_bsum<<<gN, THREADS, 0, stream>>>(deg, bsum, N);
    k_bscan<<<1, 512, 0, stream>>>(bsum, gN);
    k_offsets<<<gN, THREADS, 0, stream>>>(deg, bsum, off, dinv, N, E);
    k_bucket<<<gE, THREADS, 0, stream>>>(src, dst, rank, off, csr_src, E);

    // layer 1: A = bf16((x@W1)*dinv) ; B = bf16(relu(dn*(sum+self)+b1))
    k_gemm_f32<<<gTile, THREADS, 0, stream>>>(x, W1, dinv, bufA, N, IN);
    k_gcn_gather<<<gNE, THREADS, 0, stream>>>(bufA, csr_src, off, dinv, b1, bufB, N);

    // layer 2: A = bf16((B@W2)*dinv) ; fused gather+ReLU+FC+pool-scatter
    k_gemm_bf16<<<gTile, THREADS, 0, stream>>>(bufB, W2, dinv, bufA, N, 64);
    k_gcn_gather_fc<<<gNE, THREADS, 0, stream>>>(bufA, csr_src, off, dinv, b2, Wfc,
                                                 dict, pool16, N);
    k_cnt<<<gN, THREADS, 0, stream>>>(dict, cnt, N);

    // mean + bias + log_softmax
    k_final16<<<gRows, THREADS, 0, stream>>>(pool16, cnt, bfc, (float*)d_out, N);
}